// Round 4
// baseline (303.484 us; speedup 1.0000x reference)
//
#include <hip/hip_runtime.h>
#include <stdint.h>

typedef __bf16 bf16;
typedef __bf16 bf16x8 __attribute__((ext_vector_type(8)));
typedef __bf16 bf16x4 __attribute__((ext_vector_type(4)));
typedef float f32x4 __attribute__((ext_vector_type(4)));

#define N_DIM 196
#define C_DIM 768
#define B_DIM 256
#define KSTEPS 7           // 7*32 = 224 padded contraction length
#define MT1 14             // GEMM1 M-tiles (output freq k, padded to 224)
#define MT2 13             // GEMM2 N-tiles (output spatial n, padded to 208 >= 196)
#define CT 64              // channels per block
#define LPITCH 232         // T1w LDS pitch in bf16 elems (116 dw: c-stride 20 banks -> ~2-way = free)

#define D2F_ELEMS (MT1 * KSTEPS * 512)
#define EF_ELEMS  (MT2 * KSTEPS * 512)

// Precompute DCT matrices in MFMA fragment lane order:
//   frag idx = ((mt*KSTEPS + ks)*64 + lane)*8 + j
//   d2f: A-frag  A[row = mt*16 + (lane&15)][col = ks*32 + (lane>>4)*8 + j]   (row=freq k, col=spatial m)
//   ef : B-frag in swapped GEMM2: B[k = ks*32+(lane>>4)*8+j][n = mt*16+(lane&15)] = E[n][k]
__global__ void init_mats(bf16* __restrict__ d2f, bf16* __restrict__ ef) {
    int idx = blockIdx.x * 256 + threadIdx.x;
    const float PI = 3.14159265358979323846f;
    if (idx < D2F_ELEMS) {
        int j    = idx & 7;
        int lane = (idx >> 3) & 63;
        int rest = idx >> 9;
        int ks = rest % KSTEPS;
        int mt = rest / KSTEPS;
        int row = mt * 16 + (lane & 15);         // output freq k
        int col = ks * 32 + (lane >> 4) * 8 + j; // spatial m
        float v = 0.0f;
        if (row < N_DIM && col < N_DIM) {
            int t = ((2 * col + 1) * row) % (4 * N_DIM);
            v = 2.0f * cosf(PI * (float)t / (float)(2 * N_DIM));
        }
        d2f[idx] = (bf16)v;
    } else {
        int e = idx - D2F_ELEMS;
        if (e < EF_ELEMS) {
            int j    = e & 7;
            int lane = (e >> 3) & 63;
            int rest = e >> 9;
            int ks = rest % KSTEPS;
            int mt = rest / KSTEPS;
            int row = mt * 16 + (lane & 15);         // output n
            int col = ks * 32 + (lane >> 4) * 8 + j; // freq k
            float v = 0.0f;
            if (row < N_DIM && col < N_DIM) {
                if (col == 0) {
                    v = 1.0f / (float)(2 * N_DIM);   // E[n,0] = 1/(2N)
                } else {
                    int t = ((2 * row + 1) * col) % (4 * N_DIM);
                    v = cosf(PI * (float)t / (float)(2 * N_DIM)) / (float)N_DIM;
                }
            }
            ef[e] = (bf16)v;
        }
    }
}

// hardware transpose-read: lane l elem j <- column (l&15), row j of the 4x16 bf16 subtile
#define TRRD(dst, a, imm) \
    asm volatile("ds_read_b64_tr_b16 %0, %1 offset:" #imm : "=v"(dst) : "v"(a))

// One block = one batch b x 64-channel tile, 8 waves. Wave w owns tiles mt = w, w+8.
// SINGLE accumulator array shared by GEMM1 and GEMM2 (disjoint live ranges merged by
// construction -> ~32 AGPR instead of 64; R3 measured 2 blocks/CU because the compiler
// allocated acc and acc2 separately). launch_bounds(512,6): allocator targets <=85 regs.
// Phase A: stage x -> LDS subtiled [m/4][c/16][4][16] (conflict-free ds_write_b128)
// Phase B: GEMM1 T1 = D2 @ x  (A=d2f frags, B=x via ds_read_b64_tr_b16)
// Phase C: T1w = T1*w -> bf16 LDS [c][LPITCH]; re-zero acc
// Phase D: GEMM2 swapped (A = T1w from LDS, B = ef) -> float4 stores
__global__ __launch_bounds__(512, 6) void dct_fused(
        const float* __restrict__ x, const float* __restrict__ wgt,
        const bf16* __restrict__ d2f, const bf16* __restrict__ ef,
        float* __restrict__ out) {
    __shared__ bf16 lds[CT * LPITCH];   // 29,696 B; union: x-subtiled (28,672 B) then T1w

    const int b  = blockIdx.y;
    const int c0 = blockIdx.x * CT;
    const int t  = threadIdx.x;
    const int wave = t >> 6;
    const int lane = t & 63;
    const int ln15 = lane & 15;
    const int q    = lane >> 4;         // quad 0..3

    // ---- Phase A: stage x -> LDS subtiled [m>>2][c>>4][m&3][c&15], zero-pad m in [196,224)
    {
        const int cg8 = t & 7;          // c = 8*cg8
        const int mr  = t >> 3;         // 0..63
        const float* xp = x + (size_t)b * N_DIM * C_DIM + c0 + cg8 * 8;
#pragma unroll
        for (int i = 0; i < 3; ++i) {   // m = i*64+mr <= 191 < 196: unconditional
            int m = i * 64 + mr;
            float4 v0 = *(const float4*)(xp + (size_t)m * C_DIM);
            float4 v1 = *(const float4*)(xp + (size_t)m * C_DIM + 4);
            bf16x8 pv;
            pv[0] = (bf16)v0.x; pv[1] = (bf16)v0.y; pv[2] = (bf16)v0.z; pv[3] = (bf16)v0.w;
            pv[4] = (bf16)v1.x; pv[5] = (bf16)v1.y; pv[6] = (bf16)v1.z; pv[7] = (bf16)v1.w;
            *(bf16x8*)(lds + ((m >> 2) * 4 + (cg8 >> 1)) * 64 + (m & 3) * 16 + (cg8 & 1) * 8) = pv;
        }
        {
            int m = 192 + mr;           // tail: real rows 192..195, zeros 196..223
            if (m < 224) {
                float4 v0 = make_float4(0.f, 0.f, 0.f, 0.f);
                float4 v1 = v0;
                if (m < N_DIM) {
                    v0 = *(const float4*)(xp + (size_t)m * C_DIM);
                    v1 = *(const float4*)(xp + (size_t)m * C_DIM + 4);
                }
                bf16x8 pv;
                pv[0] = (bf16)v0.x; pv[1] = (bf16)v0.y; pv[2] = (bf16)v0.z; pv[3] = (bf16)v0.w;
                pv[4] = (bf16)v1.x; pv[5] = (bf16)v1.y; pv[6] = (bf16)v1.z; pv[7] = (bf16)v1.w;
                *(bf16x8*)(lds + ((m >> 2) * 4 + (cg8 >> 1)) * 64 + (m & 3) * 16 + (cg8 & 1) * 8) = pv;
            }
        }
    }
    __syncthreads();

    // ---- Phase B: GEMM1: T1[k, c] = sum_m D2[k,m] * x[m,c]
    f32x4 acc[2][4] = {};               // shared accumulator for BOTH GEMMs (32 AGPR)
    {
        const uint32_t xaddr = (uint32_t)(size_t)&lds[0] + q * 1024 + ln15 * 8;
#pragma unroll
        for (int ks = 0; ks < KSTEPS; ++ks) {
            uint32_t a = xaddr + ks * 4096;
            bf16x4 l0, l1, l2, l3, h0, h1, h2, h3;
            TRRD(l0, a, 0);   TRRD(h0, a, 512);
            TRRD(l1, a, 128); TRRD(h1, a, 640);
            TRRD(l2, a, 256); TRRD(h2, a, 768);
            TRRD(l3, a, 384); TRRD(h3, a, 896);
            bf16x8 afr[2];
#pragma unroll
            for (int ml = 0; ml < 2; ++ml) {
                int mt = wave + 8 * ml;
                if (mt < MT1)
                    afr[ml] = *(const bf16x8*)(d2f + ((size_t)(mt * KSTEPS + ks) * 64 + lane) * 8);
            }
            asm volatile("s_waitcnt lgkmcnt(0)");
            __builtin_amdgcn_sched_barrier(0);   // rule #18: keep tr consumers below the wait
            bf16x8 bb[4];
            bb[0] = __builtin_shufflevector(l0, h0, 0, 1, 2, 3, 4, 5, 6, 7);
            bb[1] = __builtin_shufflevector(l1, h1, 0, 1, 2, 3, 4, 5, 6, 7);
            bb[2] = __builtin_shufflevector(l2, h2, 0, 1, 2, 3, 4, 5, 6, 7);
            bb[3] = __builtin_shufflevector(l3, h3, 0, 1, 2, 3, 4, 5, 6, 7);
#pragma unroll
            for (int ml = 0; ml < 2; ++ml) {
                int mt = wave + 8 * ml;
                if (mt < MT1) {
#pragma unroll
                    for (int ct = 0; ct < 4; ++ct)
                        acc[ml][ct] = __builtin_amdgcn_mfma_f32_16x16x32_bf16(
                            afr[ml], bb[ct], acc[ml][ct], 0, 0, 0);
                }
            }
        }
    }
    __syncthreads();    // all tr-reads of x done before T1w overwrites the buffer

    // ---- Phase C: T1w[k,c] = T1[k,c]*w[c,k] -> bf16, stored to lds[c][k] (pitch LPITCH)
#pragma unroll
    for (int ml = 0; ml < 2; ++ml) {
        int mt = wave + 8 * ml;
        if (mt >= MT1) continue;
        int kb = mt * 16 + q * 4;       // D rows = k = mt*16 + q*4 + r
#pragma unroll
        for (int ct = 0; ct < 4; ++ct) {
            int cc = ct * 16 + ln15;
            float4 wv = make_float4(0.f, 0.f, 0.f, 0.f);
            if (kb < N_DIM)             // kb mult of 4, 196 mult of 4 -> kb+3 < 196
                wv = *(const float4*)(wgt + (size_t)(c0 + cc) * N_DIM + kb);
            bf16x4 pv;
            pv[0] = (bf16)(acc[ml][ct][0] * wv.x);
            pv[1] = (bf16)(acc[ml][ct][1] * wv.y);
            pv[2] = (bf16)(acc[ml][ct][2] * wv.z);
            pv[3] = (bf16)(acc[ml][ct][3] * wv.w);  // zeros pad k in [196,224)
            *(bf16x4*)(lds + cc * LPITCH + kb) = pv;
        }
    }
    // re-zero the shared accumulator for GEMM2 (cheap: 32 v_mov, forces AGPR reuse)
#pragma unroll
    for (int ml = 0; ml < 2; ++ml)
#pragma unroll
        for (int ct = 0; ct < 4; ++ct)
#pragma unroll
            for (int r = 0; r < 4; ++r)
                acc[ml][ct][r] = 0.0f;
    __syncthreads();

    // ---- Phase D: GEMM2 swapped: y[n,c]: A = T1w (M=c), B = ef (N=n)
    // D layout: col = n = l&15, row = c = q*4 + r  -> 4 consecutive channels per lane = float4 store
#pragma unroll
    for (int ks = 0; ks < KSTEPS; ++ks) {
        bf16x8 afr2[4];
#pragma unroll
        for (int ct = 0; ct < 4; ++ct)
            afr2[ct] = *(const bf16x8*)(lds + (ct * 16 + ln15) * LPITCH + ks * 32 + q * 8);
#pragma unroll
        for (int i = 0; i < 2; ++i) {
            int nt = wave + 8 * i;
            if (nt < MT2) {
                bf16x8 bfr = *(const bf16x8*)(ef + ((size_t)(nt * KSTEPS + ks) * 64 + lane) * 8);
#pragma unroll
                for (int ct = 0; ct < 4; ++ct)
                    acc[i][ct] = __builtin_amdgcn_mfma_f32_16x16x32_bf16(
                        afr2[ct], bfr, acc[i][ct], 0, 0, 0);
            }
        }
    }

    // ---- store y[b, n, c] fp32: one dwordx4 per tile (64 B contiguous per n-row)
#pragma unroll
    for (int i = 0; i < 2; ++i) {
        int nt = wave + 8 * i;
        if (nt >= MT2) continue;
        int n = nt * 16 + ln15;
        if (n < N_DIM) {
#pragma unroll
            for (int ct = 0; ct < 4; ++ct)
                *(f32x4*)(out + ((size_t)b * N_DIM + n) * C_DIM + c0 + ct * 16 + q * 4) =
                    acc[i][ct];
        }
    }
}

extern "C" void kernel_launch(void* const* d_in, const int* in_sizes, int n_in,
                              void* d_out, int out_size, void* d_ws, size_t ws_size,
                              hipStream_t stream) {
    const float* x   = (const float*)d_in[0];   // [256,196,768] fp32
    const float* wgt = (const float*)d_in[1];   // [768,196] fp32
    float* out = (float*)d_out;                 // [256,196,768] fp32

    bf16* d2f = (bf16*)d_ws;                    // 100,352 B
    bf16* ef  = d2f + D2F_ELEMS;                // 93,184 B  (total ~194 KB of ws)

    int tot = D2F_ELEMS + EF_ELEMS;
    init_mats<<<(tot + 255) / 256, 256, 0, stream>>>(d2f, ef);

    dim3 grid(C_DIM / CT, B_DIM);               // 12 x 256 = 3072 blocks of 8 waves
    dct_fused<<<grid, 512, 0, stream>>>(x, wgt, d2f, ef, out);
}

// Round 5
// 293.016 us; speedup vs baseline: 1.0357x; 1.0357x over previous
//
#include <hip/hip_runtime.h>
#include <stdint.h>

typedef __bf16 bf16;
typedef __bf16 bf16x8 __attribute__((ext_vector_type(8)));
typedef __bf16 bf16x4 __attribute__((ext_vector_type(4)));
typedef float f32x4 __attribute__((ext_vector_type(4)));

#define N_DIM 196
#define C_DIM 768
#define B_DIM 256
#define KSTEPS 7           // 7*32 = 224 padded contraction length
#define MT1 14             // GEMM1 M-tiles (output freq k, padded to 224)
#define MT2 13             // GEMM2 N-tiles (output spatial n, padded to 208 >= 196)
#define CT 64              // channels per block
#define LPITCH 232         // T1w LDS pitch in bf16 elems (116 dw: c-stride 20 banks -> ~2-way = free)
#define XELEMS 14336       // x subtiled region: 224*64 bf16 = 28,672 B

#define D2F_ELEMS (MT1 * KSTEPS * 512)
#define EF_ELEMS  (MT2 * KSTEPS * 512)

// Precompute DCT matrices in MFMA fragment lane order:
//   frag idx = ((mt*KSTEPS + ks)*64 + lane)*8 + j
//   d2f: A-frag  A[row = mt*16 + (lane&15)][col = ks*32 + (lane>>4)*8 + j]   (row=freq k, col=spatial m)
//   ef : B-frag in swapped GEMM2: B[k = ks*32+(lane>>4)*8+j][n = mt*16+(lane&15)] = E[n][k]
__global__ void init_mats(bf16* __restrict__ d2f, bf16* __restrict__ ef) {
    int idx = blockIdx.x * 256 + threadIdx.x;
    const float PI = 3.14159265358979323846f;
    if (idx < D2F_ELEMS) {
        int j    = idx & 7;
        int lane = (idx >> 3) & 63;
        int rest = idx >> 9;
        int ks = rest % KSTEPS;
        int mt = rest / KSTEPS;
        int row = mt * 16 + (lane & 15);         // output freq k
        int col = ks * 32 + (lane >> 4) * 8 + j; // spatial m
        float v = 0.0f;
        if (row < N_DIM && col < N_DIM) {
            int t = ((2 * col + 1) * row) % (4 * N_DIM);
            v = 2.0f * cosf(PI * (float)t / (float)(2 * N_DIM));
        }
        d2f[idx] = (bf16)v;
    } else {
        int e = idx - D2F_ELEMS;
        if (e < EF_ELEMS) {
            int j    = e & 7;
            int lane = (e >> 3) & 63;
            int rest = e >> 9;
            int ks = rest % KSTEPS;
            int mt = rest / KSTEPS;
            int row = mt * 16 + (lane & 15);         // output n
            int col = ks * 32 + (lane >> 4) * 8 + j; // freq k
            float v = 0.0f;
            if (row < N_DIM && col < N_DIM) {
                if (col == 0) {
                    v = 1.0f / (float)(2 * N_DIM);   // E[n,0] = 1/(2N)
                } else {
                    int t = ((2 * row + 1) * col) % (4 * N_DIM);
                    v = cosf(PI * (float)t / (float)(2 * N_DIM)) / (float)N_DIM;
                }
            }
            ef[e] = (bf16)v;
        }
    }
}

// hardware transpose-read: lane l elem j <- column (l&15), row j of the 4x16 bf16 subtile
#define TRRD(dst, a, imm) \
    asm volatile("ds_read_b64_tr_b16 %0, %1 offset:" #imm : "=v"(dst) : "v"(a))

// One block = one batch b x 64-channel tile, SIXTEEN waves (1024 thr). Wave w owns ONE
// 16-row output tile (mt=w GEMM1, nt=w GEMM2) -> acc = 16 AGPR, VGPR ~40 -> total <=64
// -> 8 waves/SIMD -> 2 blocks/CU = 32 waves = wave-slot max (R3/R4 sat at ~72 regs/24 waves).
// T1w gets its OWN LDS region (58,368 B total): kills the B->C WAR barrier -> 2 barriers.
// Phase A: stage x -> LDS subtiled [m/4][c/16][4][16] (conflict-free ds_write_b128)
// Phase B: GEMM1 T1 = D2 @ x  (A=d2f frag, B=x via ds_read_b64_tr_b16); waves 14,15 idle
// Phase C: T1w = T1*w -> bf16 into separate LDS region (no barrier after B!)
// Phase D: GEMM2 swapped (A = T1w from LDS, B = ef) -> float4 stores; waves 13..15 idle
__global__ __launch_bounds__(1024, 8) void dct_fused(
        const float* __restrict__ x, const float* __restrict__ wgt,
        const bf16* __restrict__ d2f, const bf16* __restrict__ ef,
        float* __restrict__ out) {
    __shared__ bf16 lds[XELEMS + CT * LPITCH];  // 28,672 + 29,696 = 58,368 B

    const int b  = blockIdx.y;
    const int c0 = blockIdx.x * CT;
    const int t  = threadIdx.x;
    const int wave = t >> 6;
    const int lane = t & 63;
    const int ln15 = lane & 15;
    const int q    = lane >> 4;         // quad 0..3

    bf16* const lds_t1w = lds + XELEMS;

    // ---- Phase A: stage x -> LDS subtiled [m>>2][c>>4][m&3][c&15], zero-pad m in [196,224)
    // elem off(m,c) = ((m>>2)*4 + (c>>4))*64 + (m&3)*16 + (c&15); each wave-inst writes a
    // bijective 64x16B cover of 8 subtiles -> conflict-free.
    {
        const int cg8 = t & 7;          // c = 8*cg8
        const int mr  = t >> 3;         // 0..127
        const float* xp = x + (size_t)b * N_DIM * C_DIM + c0 + cg8 * 8;
        {
            int m = mr;                 // 0..127 < 196: unconditional
            float4 v0 = *(const float4*)(xp + (size_t)m * C_DIM);
            float4 v1 = *(const float4*)(xp + (size_t)m * C_DIM + 4);
            bf16x8 pv;
            pv[0] = (bf16)v0.x; pv[1] = (bf16)v0.y; pv[2] = (bf16)v0.z; pv[3] = (bf16)v0.w;
            pv[4] = (bf16)v1.x; pv[5] = (bf16)v1.y; pv[6] = (bf16)v1.z; pv[7] = (bf16)v1.w;
            *(bf16x8*)(lds + ((m >> 2) * 4 + (cg8 >> 1)) * 64 + (m & 3) * 16 + (cg8 & 1) * 8) = pv;
        }
        {
            int m = 128 + mr;           // 128..255: real rows <196, zeros 196..223
            if (m < 224) {
                float4 v0 = make_float4(0.f, 0.f, 0.f, 0.f);
                float4 v1 = v0;
                if (m < N_DIM) {
                    v0 = *(const float4*)(xp + (size_t)m * C_DIM);
                    v1 = *(const float4*)(xp + (size_t)m * C_DIM + 4);
                }
                bf16x8 pv;
                pv[0] = (bf16)v0.x; pv[1] = (bf16)v0.y; pv[2] = (bf16)v0.z; pv[3] = (bf16)v0.w;
                pv[4] = (bf16)v1.x; pv[5] = (bf16)v1.y; pv[6] = (bf16)v1.z; pv[7] = (bf16)v1.w;
                *(bf16x8*)(lds + ((m >> 2) * 4 + (cg8 >> 1)) * 64 + (m & 3) * 16 + (cg8 & 1) * 8) = pv;
            }
        }
    }
    __syncthreads();

    // ---- Phase B: GEMM1: T1[k, c] = sum_m D2[k,m] * x[m,c]   (wave w -> k-tile w)
    // B-frag (elem e -> m = ks*32 + 8q + e, col c): group q reads subtile sm = ks*8 + 2q + h
    // byte addr = base + q*1024 + ln15*8 + (ks*4096 + h*512 + ct*128)
    f32x4 acc[4] = {};                  // ONE tile per wave: 16 AGPR, reused by GEMM2
    if (wave < MT1) {
        const uint32_t xaddr = (uint32_t)(size_t)&lds[0] + q * 1024 + ln15 * 8;
#pragma unroll
        for (int ks = 0; ks < KSTEPS; ++ks) {
            uint32_t a = xaddr + ks * 4096;
            bf16x4 l0, l1, l2, l3, h0, h1, h2, h3;
            TRRD(l0, a, 0);   TRRD(h0, a, 512);
            TRRD(l1, a, 128); TRRD(h1, a, 640);
            TRRD(l2, a, 256); TRRD(h2, a, 768);
            TRRD(l3, a, 384); TRRD(h3, a, 896);
            bf16x8 afr = *(const bf16x8*)(d2f + ((size_t)(wave * KSTEPS + ks) * 64 + lane) * 8);
            asm volatile("s_waitcnt lgkmcnt(0)");
            __builtin_amdgcn_sched_barrier(0);   // rule #18: keep tr consumers below the wait
            bf16x8 bb[4];
            bb[0] = __builtin_shufflevector(l0, h0, 0, 1, 2, 3, 4, 5, 6, 7);
            bb[1] = __builtin_shufflevector(l1, h1, 0, 1, 2, 3, 4, 5, 6, 7);
            bb[2] = __builtin_shufflevector(l2, h2, 0, 1, 2, 3, 4, 5, 6, 7);
            bb[3] = __builtin_shufflevector(l3, h3, 0, 1, 2, 3, 4, 5, 6, 7);
#pragma unroll
            for (int ct = 0; ct < 4; ++ct)
                acc[ct] = __builtin_amdgcn_mfma_f32_16x16x32_bf16(afr, bb[ct], acc[ct], 0, 0, 0);
        }

        // ---- Phase C (no barrier needed after B: T1w region is disjoint from x region)
        int kb = wave * 16 + q * 4;     // D rows = k = wave*16 + q*4 + r
#pragma unroll
        for (int ct = 0; ct < 4; ++ct) {
            int cc = ct * 16 + ln15;
            float4 wv = make_float4(0.f, 0.f, 0.f, 0.f);
            if (kb < N_DIM)             // kb mult of 4, 196 mult of 4 -> kb+3 < 196
                wv = *(const float4*)(wgt + (size_t)(c0 + cc) * N_DIM + kb);
            bf16x4 pv;
            pv[0] = (bf16)(acc[ct][0] * wv.x);
            pv[1] = (bf16)(acc[ct][1] * wv.y);
            pv[2] = (bf16)(acc[ct][2] * wv.z);
            pv[3] = (bf16)(acc[ct][3] * wv.w);  // zeros pad k in [196,224)
            *(bf16x4*)(lds_t1w + cc * LPITCH + kb) = pv;
        }
    }
    __syncthreads();    // all T1w writes visible before GEMM2 reads

    // ---- Phase D: GEMM2 swapped: y[n,c]: A = T1w (M=c), B = ef (N=n); wave w -> n-tile w
    // D layout: col = n = l&15, row = c = q*4 + r  -> 4 consecutive channels per lane = float4 store
    if (wave < MT2) {
#pragma unroll
        for (int ct = 0; ct < 4; ++ct)
#pragma unroll
            for (int r = 0; r < 4; ++r)
                acc[ct][r] = 0.0f;      // reuse GEMM1's AGPRs (disjoint live ranges)
#pragma unroll
        for (int ks = 0; ks < KSTEPS; ++ks) {
            bf16x8 afr2[4];
#pragma unroll
            for (int ct = 0; ct < 4; ++ct)
                afr2[ct] = *(const bf16x8*)(lds_t1w + (ct * 16 + ln15) * LPITCH + ks * 32 + q * 8);
            bf16x8 bfr = *(const bf16x8*)(ef + ((size_t)(wave * KSTEPS + ks) * 64 + lane) * 8);
#pragma unroll
            for (int ct = 0; ct < 4; ++ct)
                acc[ct] = __builtin_amdgcn_mfma_f32_16x16x32_bf16(afr2[ct], bfr, acc[ct], 0, 0, 0);
        }

        // ---- store y[b, n, c] fp32: one dwordx4 per ct (64 B contiguous per n-row)
        int n = wave * 16 + ln15;
        if (n < N_DIM) {
#pragma unroll
            for (int ct = 0; ct < 4; ++ct)
                *(f32x4*)(out + ((size_t)b * N_DIM + n) * C_DIM + c0 + ct * 16 + q * 4) =
                    acc[ct];
        }
    }
}

extern "C" void kernel_launch(void* const* d_in, const int* in_sizes, int n_in,
                              void* d_out, int out_size, void* d_ws, size_t ws_size,
                              hipStream_t stream) {
    const float* x   = (const float*)d_in[0];   // [256,196,768] fp32
    const float* wgt = (const float*)d_in[1];   // [768,196] fp32
    float* out = (float*)d_out;                 // [256,196,768] fp32

    bf16* d2f = (bf16*)d_ws;                    // 100,352 B
    bf16* ef  = d2f + D2F_ELEMS;                // 93,184 B  (total ~194 KB of ws)

    int tot = D2F_ELEMS + EF_ELEMS;
    init_mats<<<(tot + 255) / 256, 256, 0, stream>>>(d2f, ef);

    dim3 grid(C_DIM / CT, B_DIM);               // 12 x 256 = 3072 blocks of 16 waves
    dct_fused<<<grid, 1024, 0, stream>>>(x, wgt, d2f, ef, out);
}